// Round 21
// baseline (155.284 us; speedup 1.0000x reference)
//
#include <hip/hip_runtime.h>
#include <math.h>

#define DIM 512
#define HEADS 8
#define QL 225
#define VS 196
#define BATCH 4
#define EPS_BN 1e-5f

typedef __attribute__((ext_vector_type(8))) short bf16x8;
typedef __attribute__((ext_vector_type(4))) float f32x4;
typedef __attribute__((ext_vector_type(2))) float f32x2;

// ---------------- packed fp32 ops: native vector ops (compiler selects v_pk_*) ----------------
__device__ __forceinline__ f32x2 pk_fma(f32x2 a, f32x2 b, f32x2 c) {
    return __builtin_elementwise_fma(a, b, c);
}
__device__ __forceinline__ f32x2 pk_mul(f32x2 a, f32x2 b) { return a * b; }
__device__ __forceinline__ f32x2 pk_add(f32x2 a, f32x2 b) { return a + b; }
__device__ __forceinline__ f32x2 pk_max0(f32x2 a) {
    f32x2 z = {0.f, 0.f};
    return __builtin_elementwise_max(a, z);
}
// ---------------- full-wave DPP lane shifts (VALU pipe, 64-lane) ----------------
__device__ __forceinline__ float dpp_lm(float v) {   // value from lane-1
    return __int_as_float(__builtin_amdgcn_update_dpp(0, __float_as_int(v), 0x138, 0xF, 0xF, true));
}
__device__ __forceinline__ float dpp_lp(float v) {   // value from lane+1
    return __int_as_float(__builtin_amdgcn_update_dpp(0, __float_as_int(v), 0x130, 0xF, 0xF, true));
}
// force a block-uniform float into an SGPR
__device__ __forceinline__ float sgpr_f(float x) {
    return __int_as_float(__builtin_amdgcn_readfirstlane(__float_as_int(x)));
}

// ---------------- fp32 -> bf16 pack helpers ----------------
__device__ __forceinline__ unsigned cvt_pk_bf16(float lo, float hi) {
    unsigned r;
    asm("v_cvt_pk_bf16_f32 %0, %1, %2" : "=v"(r) : "v"(lo), "v"(hi));
    return r;
}
__device__ __forceinline__ uint4 ld_cvt8(const float* p) {
    float4 x = *(const float4*)p;
    float4 y = *(const float4*)(p + 4);
    uint4 r;
    r.x = cvt_pk_bf16(x.x, x.y);
    r.y = cvt_pk_bf16(x.z, x.w);
    r.z = cvt_pk_bf16(y.x, y.y);
    r.w = cvt_pk_bf16(y.z, y.w);
    return r;
}
__device__ __forceinline__ uint4 ld_cvt8s(const float* p, const float* p2) {
    float4 x = *(const float4*)p;
    float4 y = *(const float4*)(p + 4);
    if (p2) {
        float4 x2 = *(const float4*)p2;
        float4 y2 = *(const float4*)(p2 + 4);
        x.x += x2.x; x.y += x2.y; x.z += x2.z; x.w += x2.w;
        y.x += y2.x; y.y += y2.y; y.z += y2.z; y.w += y2.w;
    }
    uint4 r;
    r.x = cvt_pk_bf16(x.x, x.y);
    r.y = cvt_pk_bf16(x.z, x.w);
    r.z = cvt_pk_bf16(y.x, y.y);
    r.w = cvt_pk_bf16(y.z, y.w);
    return r;
}

// ---------------- multi-job bf16-MFMA GEMM (N=K=512, 32x32 tiles, BK=128) ----------------
// BK=128: 4 K-iterations (4 MFMA + 2 staged loads each) -> half the barriers on the
// latency-bound per-block critical chain vs BK=64.
struct GJob {
    const float* A; const float* W; const float* bias; const float* Add; float* Out;
    const float* A2lo; const float* A2hi;
    long aBS, aOff, addBS, addOff;
    int aRows, addRows, M, relu;
    float scale; int a2split; int pad1, pad2;
};
struct GJobs { GJob j[4]; };

template<int LAYER>
__global__ __launch_bounds__(256) void gemm_multi(GJobs jobs) {
    const GJob J = jobs.j[blockIdx.z];
    const int bm = blockIdx.y * 32, bn = blockIdx.x * 32;
    if (bm >= J.M) return;
    __shared__ __align__(16) ushort As[32][136];
    __shared__ __align__(16) ushort Bs[32][136];
    const int tid = threadIdx.x;
    const int srow = tid >> 3, skq = tid & 7;   // row 0..31, 16-float k-chunk
    const float *ap = nullptr, *ap2 = nullptr;
    {
        int m0 = bm + srow;
        if (m0 < J.M) {
            int bb = m0 / J.aRows; int r = m0 - bb * J.aRows;
            ap = J.A + bb * J.aBS + J.aOff + (long)r * 512 + skq * 16;
            if (J.A2lo) {
                ap2 = (m0 < J.a2split ? J.A2lo + (long)m0 * 512
                                      : J.A2hi + (long)(m0 - J.a2split) * 512) + skq * 16;
            }
        }
    }
    const float* bp = J.W + (long)(bn + srow) * 512 + skq * 16;

    const int lane = tid & 63, wid = tid >> 6;
    const int wr = wid >> 1, wc = wid & 1;      // 2x2 wave grid of 16x16 quadrants
    const int lr = lane & 15, kg = lane >> 4;

    f32x4 acc = {};

    uint4 a0 = {0u,0u,0u,0u}, a1 = {0u,0u,0u,0u};
    if (ap) { a0 = ld_cvt8s(ap, ap2); a1 = ld_cvt8s(ap + 8, ap2 ? ap2 + 8 : nullptr); }
    uint4 b0 = ld_cvt8(bp), b1 = ld_cvt8(bp + 8);

    for (int kt = 0; kt < 512; kt += 128) {
        __syncthreads();
        *(uint4*)&As[srow][skq * 16]     = a0;
        *(uint4*)&As[srow][skq * 16 + 8] = a1;
        *(uint4*)&Bs[srow][skq * 16]     = b0;
        *(uint4*)&Bs[srow][skq * 16 + 8] = b1;
        __syncthreads();
        if (kt + 128 < 512) {
            if (ap) {
                a0 = ld_cvt8s(ap + kt + 128, ap2 ? ap2 + kt + 128 : nullptr);
                a1 = ld_cvt8s(ap + kt + 136, ap2 ? ap2 + kt + 136 : nullptr);
            }
            b0 = ld_cvt8(bp + kt + 128); b1 = ld_cvt8(bp + kt + 136);
        }
#pragma unroll
        for (int kf = 0; kf < 4; kf++) {
            bf16x8 av = *(const bf16x8*)&As[wr * 16 + lr][kf * 32 + kg * 8];
            bf16x8 bv = *(const bf16x8*)&Bs[wc * 16 + lr][kf * 32 + kg * 8];
            acc = __builtin_amdgcn_mfma_f32_16x16x32_bf16(av, bv, acc, 0, 0, 0);
        }
    }

#pragma unroll
    for (int r = 0; r < 4; r++) {
        int m = bm + wr * 16 + kg * 4 + r;
        if (m >= J.M) continue;
        const float* addrow = nullptr;
        if (J.Add) {
            int bb2 = m / J.addRows; int rr = m - bb2 * J.addRows;
            addrow = J.Add + bb2 * J.addBS + J.addOff + (long)rr * 512;
        }
        int n = bn + wc * 16 + lr;
        float v = acc[r] * J.scale;
        if (J.bias) v += J.bias[n];
        if (J.relu) v = fmaxf(v, 0.f);
        if (addrow) v += addrow[n];
        J.Out[(long)m * 512 + n] = v;
    }
}

// ---------------- attention 1 via MFMA (R13-proven): P^T[n][q] = softmax_n(q·k) ----
__global__ __launch_bounds__(256) void attn1_mfma(const float* __restrict__ qs,
                                                  const float* __restrict__ ks,
                                                  float* __restrict__ P) {
    int bid = blockIdx.x;          // 128 = b(4) x h(8) x qt(4)
    int qt = bid & 3;
    int h = (bid >> 2) & 7;
    int b = bid >> 5;
    int tid = threadIdx.x;
    int wave = tid >> 6, lane = tid & 63;
    int lr = lane & 15, kg = lane >> 4;
    __shared__ __align__(16) ushort Kb[208][72];
    __shared__ __align__(16) ushort Qb[64][72];
    const long qBase = ((long)(b * QL)) * DIM + h * 64;
    const long kBase = ((long)(b * VS)) * DIM + h * 64;
    {
        int r = tid >> 2, c0 = (tid & 3) * 16;
        int q = qt * 64 + r;
        uint4 lo = {0u,0u,0u,0u}, hi = {0u,0u,0u,0u};
        if (q < QL) {
            const float* s = qs + qBase + (long)q * DIM + c0;
            lo = ld_cvt8(s); hi = ld_cvt8(s + 8);
        }
        *(uint4*)&Qb[r][c0] = lo; *(uint4*)&Qb[r][c0 + 8] = hi;
    }
    {
        int c0 = (tid & 3) * 16;
#pragma unroll
        for (int i = 0; i < 4; i++) {
            int r = (tid >> 2) + 64 * i;
            if (r < 208) {
                uint4 lo = {0u,0u,0u,0u}, hi = {0u,0u,0u,0u};
                if (r < VS) {
                    const float* s = ks + kBase + (long)r * DIM + c0;
                    lo = ld_cvt8(s); hi = ld_cvt8(s + 8);
                }
                *(uint4*)&Kb[r][c0] = lo; *(uint4*)&Kb[r][c0 + 8] = hi;
            }
        }
    }
    __syncthreads();

    bf16x8 bq0 = *(const bf16x8*)&Qb[wave * 16 + lr][kg * 8];
    bf16x8 bq1 = *(const bf16x8*)&Qb[wave * 16 + lr][32 + kg * 8];
    f32x4 sc[13];
#pragma unroll
    for (int ct = 0; ct < 13; ct++) {
        bf16x8 a0 = *(const bf16x8*)&Kb[ct * 16 + lr][kg * 8];
        bf16x8 a1 = *(const bf16x8*)&Kb[ct * 16 + lr][32 + kg * 8];
        f32x4 z = {0.f, 0.f, 0.f, 0.f};
        z = __builtin_amdgcn_mfma_f32_16x16x32_bf16(a0, bq0, z, 0, 0, 0);
        z = __builtin_amdgcn_mfma_f32_16x16x32_bf16(a1, bq1, z, 0, 0, 0);
        sc[ct] = z;
    }
    float m = -1e30f;
#pragma unroll
    for (int ct = 0; ct < 13; ct++)
#pragma unroll
        for (int r = 0; r < 4; r++) {
            if (ct == 12 && kg > 0) sc[ct][r] = -1e30f;
            m = fmaxf(m, sc[ct][r]);
        }
    m = fmaxf(m, __shfl_xor(m, 16, 64));
    m = fmaxf(m, __shfl_xor(m, 32, 64));
    float s = 0.f;
#pragma unroll
    for (int ct = 0; ct < 13; ct++)
#pragma unroll
        for (int r = 0; r < 4; r++) {
            float e = expf(sc[ct][r] - m);
            sc[ct][r] = e;
            s += e;
        }
    s += __shfl_xor(s, 16, 64);
    s += __shfl_xor(s, 32, 64);
    float inv = 1.f / s;
    int q = qt * 64 + wave * 16 + lr;
    if (q < QL) {
        float* Pp = P + ((long)(b * HEADS + h)) * VS * QL + q;
#pragma unroll
        for (int ct = 0; ct < 13; ct++)
#pragma unroll
            for (int r = 0; r < 4; r++) {
                int n = ct * 16 + kg * 4 + r;
                if (n < VS) Pp[(long)n * QL] = sc[ct][r] * inv;
            }
    }
}

// ---------------- fused conv v14: v13 + bias folded into top-role partials ----
// Top-role partial slots are INITIALIZED to the bias (correct h-row(-1) semantics);
// TAw/UAw production uses pk_fma with bias-free chain replaced by fma into bias-free...
// (production: mul -> fma, same count; consume saves one pk_add per conv level).
#define CSTEP8(N, PS, TAw,TAm2, TBw,TBm1, UAw,UAm2, UBw,UBm1)                      \
{                                                                                  \
    f32x2 vn = vcol2[(N)];                                                         \
    float psm = (PS) * qm;                                                         \
    f32x2 psm2 = {psm, psm};                                                       \
    f32x2 pv = pk_mul(psm2, vn);                                                   \
    f32x2 hm, hp;                                                                  \
    hm.x = dpp_lm(pv.x); hm.y = dpp_lm(pv.y);                                      \
    hp.x = dpp_lp(pv.x); hp.y = dpp_lp(pv.y);                                      \
    f32x2 g = z2;                                                                  \
    if ((N) >= 1 && (N) <= VS) {                                                   \
        f32x2 tC = pk_fma(hp, w1p[8], pk_fma(pv, w1p[7], pk_mul(hm, w1p[6])));     \
        f32x2 sg = pk_add(pk_add(tC, TBm1), TAm2);                                 \
        g = pk_mul(pk_max0(sg), qm2);                                              \
    }                                                                              \
    TAw = pk_fma(hp, w1p[2], pk_fma(pv, w1p[1], pk_fma(hm, w1p[0], b1v2)));        \
    TBw = pk_fma(hp, w1p[5], pk_fma(pv, w1p[4], pk_mul(hm, w1p[3])));              \
    f32x2 gm, gp;                                                                  \
    gm.x = dpp_lm(g.x); gm.y = dpp_lm(g.y);                                        \
    gp.x = dpp_lp(g.x); gp.y = dpp_lp(g.y);                                        \
    if ((N) >= alo && (N) <= ahi) {                                                \
        f32x2 uC = pk_fma(gp, w2p[8], pk_fma(g, w2p[7], pk_mul(gm, w2p[6])));      \
        f32x2 s2 = pk_add(pk_add(uC, UBm1), UAm2);                                 \
        csum = pk_add(csum, pk_max0(s2));                                          \
    }                                                                              \
    UAw = pk_fma(gp, w2p[2], pk_fma(g, w2p[1], pk_fma(gm, w2p[0], b2v2)));         \
    UBw = pk_fma(gp, w2p[5], pk_fma(g, w2p[4], pk_mul(gm, w2p[3])));               \
}

#define CBODY(N0, S0, S1, S2)                                                      \
    CSTEP8(N0,     S0, tAa,tAb, tBa,tBc, uAa,uAb, uBa,uBc)                         \
    CSTEP8((N0)+1, S1, tAb,tAc, tBb,tBa, uAb,uAc, uBb,uBa)                         \
    CSTEP8((N0)+2, S2, tAc,tAa, tBc,tBb, uAc,uAa, uBc,uBb)

__global__ __launch_bounds__(256) void conv_pk_kernel(
    const float* __restrict__ P, const float* __restrict__ vs,
    const float* __restrict__ dw1, const float* __restrict__ dw2,
    const float* __restrict__ bn1g, const float* __restrict__ bn1b,
    const float* __restrict__ bn1m, const float* __restrict__ bn1v,
    const float* __restrict__ bn2g, const float* __restrict__ bn2b,
    const float* __restrict__ bn2m, const float* __restrict__ bn2v,
    float* __restrict__ m2a, float* __restrict__ m2b1, float* __restrict__ m2b2) {
    int bc = blockIdx.x;            // 2048 = b(4) x cpair(256) x half(2)
    int half = bc & 1;
    int c0 = ((bc >> 1) & 255) * 2;
    int b = bc >> 9;
    int h = c0 >> 6;
    const int no  = half ? 96 : 0;
    const int alo = half ? 100 : 2;
    const int ahi = half ? 197 : 99;
    int tid = threadIdx.x;
    int wave = tid >> 6, lane = tid & 63;
    int q = wave * 60 + lane - 2;
    bool outok = (lane >= 2 && lane <= 61 && q < QL);
    float qm = (q >= 0 && q < QL) ? 1.f : 0.f;
    f32x2 qm2 = {qm, qm};
    int qc = min(max(q, 0), QL - 1);
    __shared__ __align__(8) f32x2 vcol2[200];   // zero-padded past VS
    if (tid < 200) {
        f32x2 t = {0.f, 0.f};
        if (tid < VS) {
            const float* vp = vs + ((long)(b * VS + tid)) * DIM + c0;
            t.x = vp[0]; t.y = vp[1];
        }
        vcol2[tid] = t;
    }
    // block-uniform constants -> SGPRs
    float s1x = bn1g[c0]     * rsqrtf(bn1v[c0]     + EPS_BN);
    float s1y = bn1g[c0 + 1] * rsqrtf(bn1v[c0 + 1] + EPS_BN);
    float s2x = bn2g[c0]     * rsqrtf(bn2v[c0]     + EPS_BN);
    float s2y = bn2g[c0 + 1] * rsqrtf(bn2v[c0 + 1] + EPS_BN);
    f32x2 b1v2 = {sgpr_f(bn1b[c0] - bn1m[c0] * s1x), sgpr_f(bn1b[c0 + 1] - bn1m[c0 + 1] * s1y)};
    f32x2 b2v2 = {sgpr_f(bn2b[c0] - bn2m[c0] * s2x), sgpr_f(bn2b[c0 + 1] - bn2m[c0 + 1] * s2y)};
    f32x2 w1p[9], w2p[9];
#pragma unroll
    for (int i = 0; i < 9; i++) {
        w1p[i].x = sgpr_f(dw1[c0 * 9 + i] * s1x);
        w1p[i].y = sgpr_f(dw1[(c0 + 1) * 9 + i] * s1y);
        w2p[i].x = sgpr_f(dw2[c0 * 9 + i] * s2x);
        w2p[i].y = sgpr_f(dw2[(c0 + 1) * 9 + i] * s2y);
    }
    const float* Pp = P + ((long)(b * HEADS + h)) * VS * QL;
    const float* pqb = Pp + qc;               // clamped per-lane column pointer
    __syncthreads();
    const f32x2 z2 = {0.f, 0.f};
    // top-role partials init to bias (h/h1 row -1 semantics); mid-role init 0
    f32x2 tAa = b1v2, tAb = b1v2, tAc = b1v2, tBa = z2, tBb = z2, tBc = z2;
    f32x2 uAa = b2v2, uAb = b2v2, uAc = b2v2, uBa = z2, uBb = z2, uBc = z2;
    f32x2 csum = z2;
    float ps0 = pqb[(long)(no + 0) * QL];
    float ps1 = pqb[(long)(no + 1) * QL];
    float ps2v = pqb[(long)(no + 2) * QL];
    const float* pq = pqb + (long)(no + 3) * QL;
    // 32 bodies with unguarded pointer-walk prefetch (rows <= no+98 <= 194, always valid)
    for (int k = 0; k < 32; k++) {
        float pn0 = pq[0];
        float pn1 = pq[QL];
        float pn2 = pq[2 * QL];
        int N0 = no + k * 3;
        CBODY(N0, ps0, ps1, ps2v)
        ps0 = pn0; ps1 = pn1; ps2v = pn2;
        pq += 3 * QL;
    }
    // tail: rows no+99..101 may exceed VS -> guarded one-time loads
    float pt0 = (no + 99  < VS) ? pq[0]      : 0.f;
    float pt1 = (no + 100 < VS) ? pq[QL]     : 0.f;
    float pt2 = (no + 101 < VS) ? pq[2 * QL] : 0.f;
    { int N0 = no + 96; CBODY(N0, ps0, ps1, ps2v) }
    ps0 = pt0; ps1 = pt1; ps2v = pt2;
    { int N0 = no + 99; CBODY(N0, ps0, ps1, ps2v) }
    if (outok) {
        const float inv = 1.f / (float)VS;
        f32x2 o = csum * inv;
        int row = b * QL + q;
        if (!half) {
            *(f32x2*)&m2a[(long)row * 512 + c0] = o;
        } else {
            float* dst = (row < 784) ? (m2b1 + (long)row * 512) : (m2b2 + (long)(row - 784) * 512);
            *(f32x2*)&dst[c0] = o;
        }
    }
}

// ---------------- attention 2 via MFMA (R10-proven) ----------------
__global__ __launch_bounds__(256) void attn2_mfma(const float* __restrict__ Qm,
                                                  const float* __restrict__ Km,
                                                  const float* __restrict__ Vm,
                                                  float* __restrict__ O) {
    int bid = blockIdx.x;          // 128 = b(4) x h(8) x nq(4)
    int nq = bid & 3;
    int h = (bid >> 2) & 7;
    int b = bid >> 5;
    int n0 = nq * 64;
    int tid = threadIdx.x;
    int wave = tid >> 6, lane = tid & 63;
    int lr = lane & 15, kg = lane >> 4;

    __shared__ __align__(16) char smem[77568];
    ushort (*VT)[264] = (ushort(*)[264])smem;            // [64][264]  VT[d][q]
    ushort (*Qb)[72]  = (ushort(*)[72])(smem + 33792);   // [64][72]
    ushort (*Kb)[72]  = (ushort(*)[72])(smem + 43008);   // [240][72]
    ushort (*Pl)[264] = (ushort(*)[264])(smem + 33792);  // [64][264] aliases Qb/Kb

    const long qmBase = ((long)(b * VS)) * DIM + h * 64;
    const long kmBase = ((long)(b * QL)) * DIM + h * 64;

    {
        int r = tid >> 2, c0 = (tid & 3) * 16;
        int n = min(n0 + r, VS - 1);
        const float* src = Qm + qmBase + (long)n * DIM + c0;
        *(uint4*)&Qb[r][c0]     = ld_cvt8(src);
        *(uint4*)&Qb[r][c0 + 8] = ld_cvt8(src + 8);
    }
    {
        int c0 = (tid & 3) * 16;
#pragma unroll
        for (int i = 0; i < 4; i++) {
            int r = (tid >> 2) + 64 * i;
            if (r < 240) {
                uint4 lo = {0u,0u,0u,0u}, hi = {0u,0u,0u,0u};
                if (r < QL) {
                    const float* src = Km + kmBase + (long)r * DIM + c0;
                    lo = ld_cvt8(src); hi = ld_cvt8(src + 8);
                }
                *(uint4*)&Kb[r][c0]     = lo;
                *(uint4*)&Kb[r][c0 + 8] = hi;
            }
        }
    }
    {
        int c0 = (tid & 3) * 16;
#pragma unroll
        for (int i = 0; i < 4; i++) {
            int qq = (tid >> 2) + 64 * i;
            if (qq < 240) {
                ushort u[16];
                if (qq < QL) {
                    const float* src = Vm + kmBase + (long)qq * DIM + c0;
                    *(uint4*)&u[0] = ld_cvt8(src);
                    *(uint4*)&u[8] = ld_cvt8(src + 8);
                } else {
#pragma unroll
                    for (int j = 0; j < 16; j++) u[j] = 0;
                }
#pragma unroll
                for (int j = 0; j < 16; j++) VT[c0 + j][qq] = u[j];
            }
        }
        int d = tid >> 2, qz = 240 + (tid & 3) * 4;
#pragma unroll
        for (int j = 0; j < 4; j++) VT[d][qz + j] = 0;
    }
    __syncthreads();

    bf16x8 a0 = *(const bf16x8*)&Qb[wave * 16 + lr][kg * 8];
    bf16x8 a1 = *(const bf16x8*)&Qb[wave * 16 + lr][32 + kg * 8];
    f32x4 sc[15];
#pragma unroll
    for (int ct = 0; ct < 15; ct++) {
        bf16x8 b0 = *(const bf16x8*)&Kb[ct * 16 + lr][kg * 8];
        bf16x8 b1 = *(const bf16x8*)&Kb[ct * 16 + lr][32 + kg * 8];
        f32x4 z = {0.f, 0.f, 0.f, 0.f};
        z = __builtin_amdgcn_mfma_f32_16x16x32_bf16(a0, b0, z, 0, 0, 0);
        z = __builtin_amdgcn_mfma_f32_16x16x32_bf16(a1, b1, z, 0, 0, 0);
        sc[ct] = z;
    }
    __syncthreads();

    const float scl = 0.044194173824159216f;
    float pinv[4];
#pragma unroll
    for (int r = 0; r < 4; r++) {
        float m = -1e30f;
#pragma unroll
        for (int ct = 0; ct < 15; ct++) {
            float v = sc[ct][r] * scl;
            if (ct * 16 + lr >= QL) v = -1e30f;
            sc[ct][r] = v;
            m = fmaxf(m, v);
        }
#pragma unroll
        for (int o = 1; o < 16; o <<= 1) m = fmaxf(m, __shfl_xor(m, o, 64));
        float s = 0.f;
#pragma unroll
        for (int ct = 0; ct < 15; ct++) {
            float e = expf(sc[ct][r] - m);
            sc[ct][r] = e;
            s += e;
        }
#pragma unroll
        for (int o = 1; o < 16; o <<= 1) s += __shfl_xor(s, o, 64);
        pinv[r] = 1.f / s;
    }
#pragma unroll
    for (int r = 0; r < 4; r++) {
        int row = wave * 16 + (lane >> 4) * 4 + r;
#pragma unroll
        for (int ct = 0; ct < 15; ct++) {
            float p = sc[ct][r] * pinv[r];
            Pl[row][ct * 16 + lr] = (ushort)(cvt_pk_bf16(p, p) & 0xffffu);
        }
        Pl[row][240 + lr] = 0;
    }
    __syncthreads();

    bf16x8 pa[8];
#pragma unroll
    for (int ks = 0; ks < 8; ks++)
        pa[ks] = *(const bf16x8*)&Pl[wave * 16 + lr][ks * 32 + kg * 8];
    f32x4 ov[4] = {};
#pragma unroll
    for (int dt = 0; dt < 4; dt++)
#pragma unroll
        for (int ks = 0; ks < 8; ks++) {
            bf16x8 vb = *(const bf16x8*)&VT[dt * 16 + lr][ks * 32 + kg * 8];
            ov[dt] = __builtin_amdgcn_mfma_f32_16x16x32_bf16(pa[ks], vb, ov[dt], 0, 0, 0);
        }

#pragma unroll
    for (int dt = 0; dt < 4; dt++)
#pragma unroll
        for (int r = 0; r < 4; r++) {
            int n = n0 + wave * 16 + (lane >> 4) * 4 + r;
            if (n < VS) {
                long addr = qmBase + (long)n * DIM + dt * 16 + lr;
                O[addr] = Qm[addr] + ov[dt][r];
            }
        }
}

static inline GJob mkjob(const float* A, int aRows, long aBS, long aOff,
                         const float* W, const float* bias,
                         const float* Add, int addRows, long addBS, long addOff,
                         float* Out, int M, float scale, int relu,
                         const float* A2lo = nullptr, const float* A2hi = nullptr,
                         int a2split = 0) {
    GJob j;
    j.A = A; j.W = W; j.bias = bias; j.Add = Add; j.Out = Out;
    j.A2lo = A2lo; j.A2hi = A2hi;
    j.aBS = aBS; j.aOff = aOff; j.addBS = addBS; j.addOff = addOff;
    j.aRows = aRows; j.addRows = addRows; j.M = M; j.relu = relu;
    j.scale = scale; j.a2split = a2split; j.pad1 = j.pad2 = 0;
    return j;
}

extern "C" void kernel_launch(void* const* d_in, const int* in_sizes, int n_in,
                              void* d_out, int out_size, void* d_ws, size_t ws_size,
                              hipStream_t stream) {
    const float* x     = (const float*)d_in[0];
    const float* Wq    = (const float*)d_in[1];
    const float* Wk    = (const float*)d_in[2];
    const float* Wv    = (const float*)d_in[3];
    const float* Wproj = (const float*)d_in[4];
    const float* bproj = (const float*)d_in[5];
    const float* dw1   = (const float*)d_in[6];
    const float* dw2   = (const float*)d_in[7];
    const float* pw    = (const float*)d_in[8];
    const float* bn1g  = (const float*)d_in[9];
    const float* bn1b  = (const float*)d_in[10];
    const float* bn1m  = (const float*)d_in[11];
    const float* bn1v  = (const float*)d_in[12];
    const float* bn2g  = (const float*)d_in[13];
    const float* bn2b  = (const float*)d_in[14];
    const float* bn2m  = (const float*)d_in[15];
    const float* bn2v  = (const float*)d_in[16];
    const float* mWq   = (const float*)d_in[17];
    const float* mbq   = (const float*)d_in[18];
    const float* mWk   = (const float*)d_in[19];
    const float* mbk   = (const float*)d_in[20];
    const float* mWv   = (const float*)d_in[21];
    const float* mbv   = (const float*)d_in[22];
    const float* mWo   = (const float*)d_in[23];
    const float* mbo   = (const float*)d_in[24];

    float* ws = (float*)d_ws;
    float* qs = ws;
    float* ks = ws + 460800;
    float* vsb = ws + 862208;
    float* P  = ws + 1263616;
    float* m2a = ws;            // reuses qs
    float* m2b1 = ws + 460800;  // reuses ks
    float* m2b2 = (float*)d_out;
    float* kc = ws + 1263616;
    float* Qm = ws + 1263616 + 460800;
    float* Vm = ws + 1263616 + 460800 + 401408;
    float* Km = ws;
    float* O  = ws + 460800;
    float* O2 = ws + 862208;

    const long xBS = 421L * DIM;
    const long clsOff = 196L * DIM;

    dim3 blk(256);

    // L1: q,k,v projections fused (16x29x3 = 1392 blocks)
    {
        GJobs js;
        js.j[0] = mkjob(x, QL, xBS, clsOff, Wq, nullptr, nullptr, 1, 0, 0, qs, 900, 0.125f, 0);
        js.j[1] = mkjob(x, VS, xBS, 0, Wk, nullptr, nullptr, 1, 0, 0, ks, 784, 1.f, 0);
        js.j[2] = mkjob(x, VS, xBS, 0, Wv, nullptr, nullptr, 1, 0, 0, vsb, 784, 1.f, 0);
        js.j[3] = js.j[0];
        gemm_multi<0><<<dim3(16, 29, 3), blk, 0, stream>>>(js);
    }
    attn1_mfma<<<BATCH * HEADS * 4, blk, 0, stream>>>(qs, ks, P);
    conv_pk_kernel<<<2048, blk, 0, stream>>>(P, vsb, dw1, dw2,
                                             bn1g, bn1b, bn1m, bn1v,
                                             bn2g, bn2b, bn2m, bn2v, m2a, m2b1, m2b2);
    // L2: kc = cls_cat + (m2a+m2b) @ pw^T  AND  Qm = x_sem @ mWq^T + mbq
    {
        GJobs js;
        js.j[0] = mkjob(m2a, 900, 0, 0, pw, nullptr, x, QL, xBS, clsOff, kc, 900, 1.f, 0,
                        m2b1, m2b2, 784);
        js.j[1] = mkjob(x, VS, xBS, 0, mWq, mbq, nullptr, 1, 0, 0, Qm, 784, 1.f, 0);
        js.j[2] = js.j[3] = js.j[0];
        gemm_multi<1><<<dim3(16, 29, 2), blk, 0, stream>>>(js);
    }
    // L3: Km, Vm off kc
    {
        GJobs js;
        js.j[0] = mkjob(kc, 900, 0, 0, mWk, mbk, nullptr, 1, 0, 0, Km, 900, 1.f, 0);
        js.j[1] = mkjob(kc, 900, 0, 0, mWv, mbv, nullptr, 1, 0, 0, Vm, 900, 1.f, 0);
        js.j[2] = js.j[3] = js.j[0];
        gemm_multi<2><<<dim3(16, 29, 2), blk, 0, stream>>>(js);
    }
    attn2_mfma<<<BATCH * HEADS * 4, blk, 0, stream>>>(Qm, Km, Vm, O);
    // L4: O2 = O + relu(O @ mWo^T + mbo)
    {
        GJobs js;
        js.j[0] = mkjob(O, 784, 0, 0, mWo, mbo, O, 784, 0, 0, O2, 784, 1.f, 1);
        js.j[1] = js.j[2] = js.j[3] = js.j[0];
        gemm_multi<3><<<dim3(16, 25, 1), blk, 0, stream>>>(js);
    }
    // L5: out = O2 @ Wproj^T + bproj
    {
        GJobs js;
        js.j[0] = mkjob(O2, 784, 0, 0, Wproj, bproj, nullptr, 1, 0, 0, (float*)d_out, 784, 1.f, 0);
        js.j[1] = js.j[2] = js.j[3] = js.j[0];
        gemm_multi<4><<<dim3(16, 25, 1), blk, 0, stream>>>(js);
    }
}

// Round 22
// 147.598 us; speedup vs baseline: 1.0521x; 1.0521x over previous
//
#include <hip/hip_runtime.h>
#include <math.h>

#define DIM 512
#define HEADS 8
#define QL 225
#define VS 196
#define BATCH 4
#define EPS_BN 1e-5f

typedef __attribute__((ext_vector_type(8))) short bf16x8;
typedef __attribute__((ext_vector_type(4))) float f32x4;
typedef __attribute__((ext_vector_type(2))) float f32x2;

// ---------------- packed fp32 ops: native vector ops (compiler selects v_pk_*) ----------------
__device__ __forceinline__ f32x2 pk_fma(f32x2 a, f32x2 b, f32x2 c) {
    return __builtin_elementwise_fma(a, b, c);
}
__device__ __forceinline__ f32x2 pk_mul(f32x2 a, f32x2 b) { return a * b; }
__device__ __forceinline__ f32x2 pk_add(f32x2 a, f32x2 b) { return a + b; }
__device__ __forceinline__ f32x2 pk_max0(f32x2 a) {
    f32x2 z = {0.f, 0.f};
    return __builtin_elementwise_max(a, z);
}
// ---------------- full-wave DPP lane shifts (VALU pipe, 64-lane) ----------------
__device__ __forceinline__ float dpp_lm(float v) {   // value from lane-1
    return __int_as_float(__builtin_amdgcn_update_dpp(0, __float_as_int(v), 0x138, 0xF, 0xF, true));
}
__device__ __forceinline__ float dpp_lp(float v) {   // value from lane+1
    return __int_as_float(__builtin_amdgcn_update_dpp(0, __float_as_int(v), 0x130, 0xF, 0xF, true));
}
// force a block-uniform float into an SGPR
__device__ __forceinline__ float sgpr_f(float x) {
    return __int_as_float(__builtin_amdgcn_readfirstlane(__float_as_int(x)));
}

// ---------------- fp32 -> bf16 pack helpers ----------------
__device__ __forceinline__ unsigned cvt_pk_bf16(float lo, float hi) {
    unsigned r;
    asm("v_cvt_pk_bf16_f32 %0, %1, %2" : "=v"(r) : "v"(lo), "v"(hi));
    return r;
}
__device__ __forceinline__ uint4 ld_cvt8(const float* p) {
    float4 x = *(const float4*)p;
    float4 y = *(const float4*)(p + 4);
    uint4 r;
    r.x = cvt_pk_bf16(x.x, x.y);
    r.y = cvt_pk_bf16(x.z, x.w);
    r.z = cvt_pk_bf16(y.x, y.y);
    r.w = cvt_pk_bf16(y.z, y.w);
    return r;
}
__device__ __forceinline__ uint4 ld_cvt8s(const float* p, const float* p2) {
    float4 x = *(const float4*)p;
    float4 y = *(const float4*)(p + 4);
    if (p2) {
        float4 x2 = *(const float4*)p2;
        float4 y2 = *(const float4*)(p2 + 4);
        x.x += x2.x; x.y += x2.y; x.z += x2.z; x.w += x2.w;
        y.x += y2.x; y.y += y2.y; y.z += y2.z; y.w += y2.w;
    }
    uint4 r;
    r.x = cvt_pk_bf16(x.x, x.y);
    r.y = cvt_pk_bf16(x.z, x.w);
    r.z = cvt_pk_bf16(y.x, y.y);
    r.w = cvt_pk_bf16(y.z, y.w);
    return r;
}

// ---------------- multi-job bf16-MFMA GEMM (N=K=512, 32x32 tiles, BK=64 -- R20-proven) ----------------
struct GJob {
    const float* A; const float* W; const float* bias; const float* Add; float* Out;
    const float* A2lo; const float* A2hi;
    long aBS, aOff, addBS, addOff;
    int aRows, addRows, M, relu;
    float scale; int a2split; int pad1, pad2;
};
struct GJobs { GJob j[4]; };

template<int LAYER>
__global__ __launch_bounds__(256) void gemm_multi(GJobs jobs) {
    const GJob J = jobs.j[blockIdx.z];
    const int bm = blockIdx.y * 32, bn = blockIdx.x * 32;
    if (bm >= J.M) return;
    __shared__ __align__(16) ushort As[32][72];
    __shared__ __align__(16) ushort Bs[32][72];
    const int tid = threadIdx.x;
    const int srow = tid >> 3, skq = tid & 7;
    const float *ap = nullptr, *ap2 = nullptr;
    {
        int m0 = bm + srow;
        if (m0 < J.M) {
            int bb = m0 / J.aRows; int r = m0 - bb * J.aRows;
            ap = J.A + bb * J.aBS + J.aOff + (long)r * 512 + skq * 8;
            if (J.A2lo) {
                ap2 = (m0 < J.a2split ? J.A2lo + (long)m0 * 512
                                      : J.A2hi + (long)(m0 - J.a2split) * 512) + skq * 8;
            }
        }
    }
    const float* bp = J.W + (long)(bn + srow) * 512 + skq * 8;

    const int lane = tid & 63, wid = tid >> 6;
    const int wr = wid >> 1, wc = wid & 1;
    const int lr = lane & 15, kg = lane >> 4;

    f32x4 acc = {};

    uint4 a01 = {0u,0u,0u,0u};
    if (ap) a01 = ld_cvt8s(ap, ap2);
    uint4 b01 = ld_cvt8(bp);

    for (int kt = 0; kt < 512; kt += 64) {
        __syncthreads();
        *(uint4*)&As[srow][skq * 8] = a01;
        *(uint4*)&Bs[srow][skq * 8] = b01;
        __syncthreads();
        if (kt + 64 < 512) {
            if (ap) a01 = ld_cvt8s(ap + kt + 64, ap2 ? ap2 + kt + 64 : nullptr);
            b01 = ld_cvt8(bp + kt + 64);
        }
        bf16x8 a0 = *(const bf16x8*)&As[wr * 16 + lr][kg * 8];
        bf16x8 a1 = *(const bf16x8*)&As[wr * 16 + lr][32 + kg * 8];
        bf16x8 b0 = *(const bf16x8*)&Bs[wc * 16 + lr][kg * 8];
        bf16x8 b1 = *(const bf16x8*)&Bs[wc * 16 + lr][32 + kg * 8];
        acc = __builtin_amdgcn_mfma_f32_16x16x32_bf16(a0, b0, acc, 0, 0, 0);
        acc = __builtin_amdgcn_mfma_f32_16x16x32_bf16(a1, b1, acc, 0, 0, 0);
    }

#pragma unroll
    for (int r = 0; r < 4; r++) {
        int m = bm + wr * 16 + kg * 4 + r;
        if (m >= J.M) continue;
        const float* addrow = nullptr;
        if (J.Add) {
            int bb2 = m / J.addRows; int rr = m - bb2 * J.addRows;
            addrow = J.Add + bb2 * J.addBS + J.addOff + (long)rr * 512;
        }
        int n = bn + wc * 16 + lr;
        float v = acc[r] * J.scale;
        if (J.bias) v += J.bias[n];
        if (J.relu) v = fmaxf(v, 0.f);
        if (addrow) v += addrow[n];
        J.Out[(long)m * 512 + n] = v;
    }
}

// ---------------- attention 1 via MFMA (R13-proven): P^T[n][q] = softmax_n(q·k) ----
__global__ __launch_bounds__(256) void attn1_mfma(const float* __restrict__ qs,
                                                  const float* __restrict__ ks,
                                                  float* __restrict__ P) {
    int bid = blockIdx.x;          // 128 = b(4) x h(8) x qt(4)
    int qt = bid & 3;
    int h = (bid >> 2) & 7;
    int b = bid >> 5;
    int tid = threadIdx.x;
    int wave = tid >> 6, lane = tid & 63;
    int lr = lane & 15, kg = lane >> 4;
    __shared__ __align__(16) ushort Kb[208][72];
    __shared__ __align__(16) ushort Qb[64][72];
    const long qBase = ((long)(b * QL)) * DIM + h * 64;
    const long kBase = ((long)(b * VS)) * DIM + h * 64;
    {
        int r = tid >> 2, c0 = (tid & 3) * 16;
        int q = qt * 64 + r;
        uint4 lo = {0u,0u,0u,0u}, hi = {0u,0u,0u,0u};
        if (q < QL) {
            const float* s = qs + qBase + (long)q * DIM + c0;
            lo = ld_cvt8(s); hi = ld_cvt8(s + 8);
        }
        *(uint4*)&Qb[r][c0] = lo; *(uint4*)&Qb[r][c0 + 8] = hi;
    }
    {
        int c0 = (tid & 3) * 16;
#pragma unroll
        for (int i = 0; i < 4; i++) {
            int r = (tid >> 2) + 64 * i;
            if (r < 208) {
                uint4 lo = {0u,0u,0u,0u}, hi = {0u,0u,0u,0u};
                if (r < VS) {
                    const float* s = ks + kBase + (long)r * DIM + c0;
                    lo = ld_cvt8(s); hi = ld_cvt8(s + 8);
                }
                *(uint4*)&Kb[r][c0] = lo; *(uint4*)&Kb[r][c0 + 8] = hi;
            }
        }
    }
    __syncthreads();

    bf16x8 bq0 = *(const bf16x8*)&Qb[wave * 16 + lr][kg * 8];
    bf16x8 bq1 = *(const bf16x8*)&Qb[wave * 16 + lr][32 + kg * 8];
    f32x4 sc[13];
#pragma unroll
    for (int ct = 0; ct < 13; ct++) {
        bf16x8 a0 = *(const bf16x8*)&Kb[ct * 16 + lr][kg * 8];
        bf16x8 a1 = *(const bf16x8*)&Kb[ct * 16 + lr][32 + kg * 8];
        f32x4 z = {0.f, 0.f, 0.f, 0.f};
        z = __builtin_amdgcn_mfma_f32_16x16x32_bf16(a0, bq0, z, 0, 0, 0);
        z = __builtin_amdgcn_mfma_f32_16x16x32_bf16(a1, bq1, z, 0, 0, 0);
        sc[ct] = z;
    }
    float m = -1e30f;
#pragma unroll
    for (int ct = 0; ct < 13; ct++)
#pragma unroll
        for (int r = 0; r < 4; r++) {
            if (ct == 12 && kg > 0) sc[ct][r] = -1e30f;
            m = fmaxf(m, sc[ct][r]);
        }
    m = fmaxf(m, __shfl_xor(m, 16, 64));
    m = fmaxf(m, __shfl_xor(m, 32, 64));
    float s = 0.f;
#pragma unroll
    for (int ct = 0; ct < 13; ct++)
#pragma unroll
        for (int r = 0; r < 4; r++) {
            float e = expf(sc[ct][r] - m);
            sc[ct][r] = e;
            s += e;
        }
    s += __shfl_xor(s, 16, 64);
    s += __shfl_xor(s, 32, 64);
    float inv = 1.f / s;
    int q = qt * 64 + wave * 16 + lr;
    if (q < QL) {
        float* Pp = P + ((long)(b * HEADS + h)) * VS * QL + q;
#pragma unroll
        for (int ct = 0; ct < 13; ct++)
#pragma unroll
            for (int r = 0; r < 4; r++) {
                int n = ct * 16 + kg * 4 + r;
                if (n < VS) Pp[(long)n * QL] = sc[ct][r] * inv;
            }
    }
}

// ---------------- fused conv v14 (R21-proven): DPP + SGPR weights + bias-fold ----
#define CSTEP8(N, PS, TAw,TAm2, TBw,TBm1, UAw,UAm2, UBw,UBm1)                      \
{                                                                                  \
    f32x2 vn = vcol2[(N)];                                                         \
    float psm = (PS) * qm;                                                         \
    f32x2 psm2 = {psm, psm};                                                       \
    f32x2 pv = pk_mul(psm2, vn);                                                   \
    f32x2 hm, hp;                                                                  \
    hm.x = dpp_lm(pv.x); hm.y = dpp_lm(pv.y);                                      \
    hp.x = dpp_lp(pv.x); hp.y = dpp_lp(pv.y);                                      \
    f32x2 g = z2;                                                                  \
    if ((N) >= 1 && (N) <= VS) {                                                   \
        f32x2 tC = pk_fma(hp, w1p[8], pk_fma(pv, w1p[7], pk_mul(hm, w1p[6])));     \
        f32x2 sg = pk_add(pk_add(tC, TBm1), TAm2);                                 \
        g = pk_mul(pk_max0(sg), qm2);                                              \
    }                                                                              \
    TAw = pk_fma(hp, w1p[2], pk_fma(pv, w1p[1], pk_fma(hm, w1p[0], b1v2)));        \
    TBw = pk_fma(hp, w1p[5], pk_fma(pv, w1p[4], pk_mul(hm, w1p[3])));              \
    f32x2 gm, gp;                                                                  \
    gm.x = dpp_lm(g.x); gm.y = dpp_lm(g.y);                                        \
    gp.x = dpp_lp(g.x); gp.y = dpp_lp(g.y);                                        \
    if ((N) >= alo && (N) <= ahi) {                                                \
        f32x2 uC = pk_fma(gp, w2p[8], pk_fma(g, w2p[7], pk_mul(gm, w2p[6])));      \
        f32x2 s2 = pk_add(pk_add(uC, UBm1), UAm2);                                 \
        csum = pk_add(csum, pk_max0(s2));                                          \
    }                                                                              \
    UAw = pk_fma(gp, w2p[2], pk_fma(g, w2p[1], pk_fma(gm, w2p[0], b2v2)));         \
    UBw = pk_fma(gp, w2p[5], pk_fma(g, w2p[4], pk_mul(gm, w2p[3])));               \
}

#define CBODY(N0, S0, S1, S2)                                                      \
    CSTEP8(N0,     S0, tAa,tAb, tBa,tBc, uAa,uAb, uBa,uBc)                         \
    CSTEP8((N0)+1, S1, tAb,tAc, tBb,tBa, uAb,uAc, uBb,uBa)                         \
    CSTEP8((N0)+2, S2, tAc,tAa, tBc,tBb, uAc,uAa, uBc,uBb)

__global__ __launch_bounds__(256) void conv_pk_kernel(
    const float* __restrict__ P, const float* __restrict__ vs,
    const float* __restrict__ dw1, const float* __restrict__ dw2,
    const float* __restrict__ bn1g, const float* __restrict__ bn1b,
    const float* __restrict__ bn1m, const float* __restrict__ bn1v,
    const float* __restrict__ bn2g, const float* __restrict__ bn2b,
    const float* __restrict__ bn2m, const float* __restrict__ bn2v,
    float* __restrict__ m2a, float* __restrict__ m2b1, float* __restrict__ m2b2) {
    int bc = blockIdx.x;            // 2048 = b(4) x cpair(256) x half(2)
    int half = bc & 1;
    int c0 = ((bc >> 1) & 255) * 2;
    int b = bc >> 9;
    int h = c0 >> 6;
    const int no  = half ? 96 : 0;
    const int alo = half ? 100 : 2;
    const int ahi = half ? 197 : 99;
    int tid = threadIdx.x;
    int wave = tid >> 6, lane = tid & 63;
    int q = wave * 60 + lane - 2;
    bool outok = (lane >= 2 && lane <= 61 && q < QL);
    float qm = (q >= 0 && q < QL) ? 1.f : 0.f;
    f32x2 qm2 = {qm, qm};
    int qc = min(max(q, 0), QL - 1);
    __shared__ __align__(8) f32x2 vcol2[200];   // zero-padded past VS
    if (tid < 200) {
        f32x2 t = {0.f, 0.f};
        if (tid < VS) {
            const float* vp = vs + ((long)(b * VS + tid)) * DIM + c0;
            t.x = vp[0]; t.y = vp[1];
        }
        vcol2[tid] = t;
    }
    // block-uniform constants -> SGPRs
    float s1x = bn1g[c0]     * rsqrtf(bn1v[c0]     + EPS_BN);
    float s1y = bn1g[c0 + 1] * rsqrtf(bn1v[c0 + 1] + EPS_BN);
    float s2x = bn2g[c0]     * rsqrtf(bn2v[c0]     + EPS_BN);
    float s2y = bn2g[c0 + 1] * rsqrtf(bn2v[c0 + 1] + EPS_BN);
    f32x2 b1v2 = {sgpr_f(bn1b[c0] - bn1m[c0] * s1x), sgpr_f(bn1b[c0 + 1] - bn1m[c0 + 1] * s1y)};
    f32x2 b2v2 = {sgpr_f(bn2b[c0] - bn2m[c0] * s2x), sgpr_f(bn2b[c0 + 1] - bn2m[c0 + 1] * s2y)};
    f32x2 w1p[9], w2p[9];
#pragma unroll
    for (int i = 0; i < 9; i++) {
        w1p[i].x = sgpr_f(dw1[c0 * 9 + i] * s1x);
        w1p[i].y = sgpr_f(dw1[(c0 + 1) * 9 + i] * s1y);
        w2p[i].x = sgpr_f(dw2[c0 * 9 + i] * s2x);
        w2p[i].y = sgpr_f(dw2[(c0 + 1) * 9 + i] * s2y);
    }
    const float* Pp = P + ((long)(b * HEADS + h)) * VS * QL;
    const float* pqb = Pp + qc;               // clamped per-lane column pointer
    __syncthreads();
    const f32x2 z2 = {0.f, 0.f};
    // top-role partials init to bias (h/h1 row -1 semantics); mid-role init 0
    f32x2 tAa = b1v2, tAb = b1v2, tAc = b1v2, tBa = z2, tBb = z2, tBc = z2;
    f32x2 uAa = b2v2, uAb = b2v2, uAc = b2v2, uBa = z2, uBb = z2, uBc = z2;
    f32x2 csum = z2;
    float ps0 = pqb[(long)(no + 0) * QL];
    float ps1 = pqb[(long)(no + 1) * QL];
    float ps2v = pqb[(long)(no + 2) * QL];
    const float* pq = pqb + (long)(no + 3) * QL;
    // 32 bodies with unguarded pointer-walk prefetch (rows <= no+98 <= 194, always valid)
    for (int k = 0; k < 32; k++) {
        float pn0 = pq[0];
        float pn1 = pq[QL];
        float pn2 = pq[2 * QL];
        int N0 = no + k * 3;
        CBODY(N0, ps0, ps1, ps2v)
        ps0 = pn0; ps1 = pn1; ps2v = pn2;
        pq += 3 * QL;
    }
    // tail: rows no+99..101 may exceed VS -> guarded one-time loads
    float pt0 = (no + 99  < VS) ? pq[0]      : 0.f;
    float pt1 = (no + 100 < VS) ? pq[QL]     : 0.f;
    float pt2 = (no + 101 < VS) ? pq[2 * QL] : 0.f;
    { int N0 = no + 96; CBODY(N0, ps0, ps1, ps2v) }
    ps0 = pt0; ps1 = pt1; ps2v = pt2;
    { int N0 = no + 99; CBODY(N0, ps0, ps1, ps2v) }
    if (outok) {
        const float inv = 1.f / (float)VS;
        f32x2 o = csum * inv;
        int row = b * QL + q;
        if (!half) {
            *(f32x2*)&m2a[(long)row * 512 + c0] = o;
        } else {
            float* dst = (row < 784) ? (m2b1 + (long)row * 512) : (m2b2 + (long)(row - 784) * 512);
            *(f32x2*)&dst[c0] = o;
        }
    }
}

// ---------------- attention 2 via MFMA (R10-proven) ----------------
__global__ __launch_bounds__(256) void attn2_mfma(const float* __restrict__ Qm,
                                                  const float* __restrict__ Km,
                                                  const float* __restrict__ Vm,
                                                  float* __restrict__ O) {
    int bid = blockIdx.x;          // 128 = b(4) x h(8) x nq(4)
    int nq = bid & 3;
    int h = (bid >> 2) & 7;
    int b = bid >> 5;
    int n0 = nq * 64;
    int tid = threadIdx.x;
    int wave = tid >> 6, lane = tid & 63;
    int lr = lane & 15, kg = lane >> 4;

    __shared__ __align__(16) char smem[77568];
    ushort (*VT)[264] = (ushort(*)[264])smem;            // [64][264]  VT[d][q]
    ushort (*Qb)[72]  = (ushort(*)[72])(smem + 33792);   // [64][72]
    ushort (*Kb)[72]  = (ushort(*)[72])(smem + 43008);   // [240][72]
    ushort (*Pl)[264] = (ushort(*)[264])(smem + 33792);  // [64][264] aliases Qb/Kb

    const long qmBase = ((long)(b * VS)) * DIM + h * 64;
    const long kmBase = ((long)(b * QL)) * DIM + h * 64;

    {
        int r = tid >> 2, c0 = (tid & 3) * 16;
        int n = min(n0 + r, VS - 1);
        const float* src = Qm + qmBase + (long)n * DIM + c0;
        *(uint4*)&Qb[r][c0]     = ld_cvt8(src);
        *(uint4*)&Qb[r][c0 + 8] = ld_cvt8(src + 8);
    }
    {
        int c0 = (tid & 3) * 16;
#pragma unroll
        for (int i = 0; i < 4; i++) {
            int r = (tid >> 2) + 64 * i;
            if (r < 240) {
                uint4 lo = {0u,0u,0u,0u}, hi = {0u,0u,0u,0u};
                if (r < QL) {
                    const float* src = Km + kmBase + (long)r * DIM + c0;
                    lo = ld_cvt8(src); hi = ld_cvt8(src + 8);
                }
                *(uint4*)&Kb[r][c0]     = lo;
                *(uint4*)&Kb[r][c0 + 8] = hi;
            }
        }
    }
    {
        int c0 = (tid & 3) * 16;
#pragma unroll
        for (int i = 0; i < 4; i++) {
            int qq = (tid >> 2) + 64 * i;
            if (qq < 240) {
                ushort u[16];
                if (qq < QL) {
                    const float* src = Vm + kmBase + (long)qq * DIM + c0;
                    *(uint4*)&u[0] = ld_cvt8(src);
                    *(uint4*)&u[8] = ld_cvt8(src + 8);
                } else {
#pragma unroll
                    for (int j = 0; j < 16; j++) u[j] = 0;
                }
#pragma unroll
                for (int j = 0; j < 16; j++) VT[c0 + j][qq] = u[j];
            }
        }
        int d = tid >> 2, qz = 240 + (tid & 3) * 4;
#pragma unroll
        for (int j = 0; j < 4; j++) VT[d][qz + j] = 0;
    }
    __syncthreads();

    bf16x8 a0 = *(const bf16x8*)&Qb[wave * 16 + lr][kg * 8];
    bf16x8 a1 = *(const bf16x8*)&Qb[wave * 16 + lr][32 + kg * 8];
    f32x4 sc[15];
#pragma unroll
    for (int ct = 0; ct < 15; ct++) {
        bf16x8 b0 = *(const bf16x8*)&Kb[ct * 16 + lr][kg * 8];
        bf16x8 b1 = *(const bf16x8*)&Kb[ct * 16 + lr][32 + kg * 8];
        f32x4 z = {0.f, 0.f, 0.f, 0.f};
        z = __builtin_amdgcn_mfma_f32_16x16x32_bf16(a0, b0, z, 0, 0, 0);
        z = __builtin_amdgcn_mfma_f32_16x16x32_bf16(a1, b1, z, 0, 0, 0);
        sc[ct] = z;
    }
    __syncthreads();

    const float scl = 0.044194173824159216f;
    float pinv[4];
#pragma unroll
    for (int r = 0; r < 4; r++) {
        float m = -1e30f;
#pragma unroll
        for (int ct = 0; ct < 15; ct++) {
            float v = sc[ct][r] * scl;
            if (ct * 16 + lr >= QL) v = -1e30f;
            sc[ct][r] = v;
            m = fmaxf(m, v);
        }
#pragma unroll
        for (int o = 1; o < 16; o <<= 1) m = fmaxf(m, __shfl_xor(m, o, 64));
        float s = 0.f;
#pragma unroll
        for (int ct = 0; ct < 15; ct++) {
            float e = expf(sc[ct][r] - m);
            sc[ct][r] = e;
            s += e;
        }
#pragma unroll
        for (int o = 1; o < 16; o <<= 1) s += __shfl_xor(s, o, 64);
        pinv[r] = 1.f / s;
    }
#pragma unroll
    for (int r = 0; r < 4; r++) {
        int row = wave * 16 + (lane >> 4) * 4 + r;
#pragma unroll
        for (int ct = 0; ct < 15; ct++) {
            float p = sc[ct][r] * pinv[r];
            Pl[row][ct * 16 + lr] = (ushort)(cvt_pk_bf16(p, p) & 0xffffu);
        }
        Pl[row][240 + lr] = 0;
    }
    __syncthreads();

    bf16x8 pa[8];
#pragma unroll
    for (int ks = 0; ks < 8; ks++)
        pa[ks] = *(const bf16x8*)&Pl[wave * 16 + lr][ks * 32 + kg * 8];
    f32x4 ov[4] = {};
#pragma unroll
    for (int dt = 0; dt < 4; dt++)
#pragma unroll
        for (int ks = 0; ks < 8; ks++) {
            bf16x8 vb = *(const bf16x8*)&VT[dt * 16 + lr][ks * 32 + kg * 8];
            ov[dt] = __builtin_amdgcn_mfma_f32_16x16x32_bf16(pa[ks], vb, ov[dt], 0, 0, 0);
        }

#pragma unroll
    for (int dt = 0; dt < 4; dt++)
#pragma unroll
        for (int r = 0; r < 4; r++) {
            int n = n0 + wave * 16 + (lane >> 4) * 4 + r;
            if (n < VS) {
                long addr = qmBase + (long)n * DIM + dt * 16 + lr;
                O[addr] = Qm[addr] + ov[dt][r];
            }
        }
}

static inline GJob mkjob(const float* A, int aRows, long aBS, long aOff,
                         const float* W, const float* bias,
                         const float* Add, int addRows, long addBS, long addOff,
                         float* Out, int M, float scale, int relu,
                         const float* A2lo = nullptr, const float* A2hi = nullptr,
                         int a2split = 0) {
    GJob j;
    j.A = A; j.W = W; j.bias = bias; j.Add = Add; j.Out = Out;
    j.A2lo = A2lo; j.A2hi = A2hi;
    j.aBS = aBS; j.aOff = aOff; j.addBS = addBS; j.addOff = addOff;
    j.aRows = aRows; j.addRows = addRows; j.M = M; j.relu = relu;
    j.scale = scale; j.a2split = a2split; j.pad1 = j.pad2 = 0;
    return j;
}

extern "C" void kernel_launch(void* const* d_in, const int* in_sizes, int n_in,
                              void* d_out, int out_size, void* d_ws, size_t ws_size,
                              hipStream_t stream) {
    const float* x     = (const float*)d_in[0];
    const float* Wq    = (const float*)d_in[1];
    const float* Wk    = (const float*)d_in[2];
    const float* Wv    = (const float*)d_in[3];
    const float* Wproj = (const float*)d_in[4];
    const float* bproj = (const float*)d_in[5];
    const float* dw1   = (const float*)d_in[6];
    const float* dw2   = (const float*)d_in[7];
    const float* pw    = (const float*)d_in[8];
    const float* bn1g  = (const float*)d_in[9];
    const float* bn1b  = (const float*)d_in[10];
    const float* bn1m  = (const float*)d_in[11];
    const float* bn1v  = (const float*)d_in[12];
    const float* bn2g  = (const float*)d_in[13];
    const float* bn2b  = (const float*)d_in[14];
    const float* bn2m  = (const float*)d_in[15];
    const float* bn2v  = (const float*)d_in[16];
    const float* mWq   = (const float*)d_in[17];
    const float* mbq   = (const float*)d_in[18];
    const float* mWk   = (const float*)d_in[19];
    const float* mbk   = (const float*)d_in[20];
    const float* mWv   = (const float*)d_in[21];
    const float* mbv   = (const float*)d_in[22];
    const float* mWo   = (const float*)d_in[23];
    const float* mbo   = (const float*)d_in[24];

    float* ws = (float*)d_ws;
    float* qs = ws;
    float* ks = ws + 460800;
    float* vsb = ws + 862208;
    float* P  = ws + 1263616;
    float* m2a = ws;            // reuses qs
    float* m2b1 = ws + 460800;  // reuses ks
    float* m2b2 = (float*)d_out;
    float* kc = ws + 1263616;
    float* Qm = ws + 1263616 + 460800;
    float* Vm = ws + 1263616 + 460800 + 401408;
    float* Km = ws;
    float* O  = ws + 460800;
    float* O2 = ws + 862208;

    const long xBS = 421L * DIM;
    const long clsOff = 196L * DIM;

    dim3 blk(256);

    // L1: q,k,v projections fused (16x29x3 = 1392 blocks)
    {
        GJobs js;
        js.j[0] = mkjob(x, QL, xBS, clsOff, Wq, nullptr, nullptr, 1, 0, 0, qs, 900, 0.125f, 0);
        js.j[1] = mkjob(x, VS, xBS, 0, Wk, nullptr, nullptr, 1, 0, 0, ks, 784, 1.f, 0);
        js.j[2] = mkjob(x, VS, xBS, 0, Wv, nullptr, nullptr, 1, 0, 0, vsb, 784, 1.f, 0);
        js.j[3] = js.j[0];
        gemm_multi<0><<<dim3(16, 29, 3), blk, 0, stream>>>(js);
    }
    attn1_mfma<<<BATCH * HEADS * 4, blk, 0, stream>>>(qs, ks, P);
    conv_pk_kernel<<<2048, blk, 0, stream>>>(P, vsb, dw1, dw2,
                                             bn1g, bn1b, bn1m, bn1v,
                                             bn2g, bn2b, bn2m, bn2v, m2a, m2b1, m2b2);
    // L2: kc = cls_cat + (m2a+m2b) @ pw^T  AND  Qm = x_sem @ mWq^T + mbq
    {
        GJobs js;
        js.j[0] = mkjob(m2a, 900, 0, 0, pw, nullptr, x, QL, xBS, clsOff, kc, 900, 1.f, 0,
                        m2b1, m2b2, 784);
        js.j[1] = mkjob(x, VS, xBS, 0, mWq, mbq, nullptr, 1, 0, 0, Qm, 784, 1.f, 0);
        js.j[2] = js.j[3] = js.j[0];
        gemm_multi<1><<<dim3(16, 29, 2), blk, 0, stream>>>(js);
    }
    // L3: Km, Vm off kc
    {
        GJobs js;
        js.j[0] = mkjob(kc, 900, 0, 0, mWk, mbk, nullptr, 1, 0, 0, Km, 900, 1.f, 0);
        js.j[1] = mkjob(kc, 900, 0, 0, mWv, mbv, nullptr, 1, 0, 0, Vm, 900, 1.f, 0);
        js.j[2] = js.j[3] = js.j[0];
        gemm_multi<2><<<dim3(16, 29, 2), blk, 0, stream>>>(js);
    }
    attn2_mfma<<<BATCH * HEADS * 4, blk, 0, stream>>>(Qm, Km, Vm, O);
    // L4: O2 = O + relu(O @ mWo^T + mbo)
    {
        GJobs js;
        js.j[0] = mkjob(O, 784, 0, 0, mWo, mbo, O, 784, 0, 0, O2, 784, 1.f, 1);
        js.j[1] = js.j[2] = js.j[3] = js.j[0];
        gemm_multi<3><<<dim3(16, 25, 1), blk, 0, stream>>>(js);
    }
    // L5: out = O2 @ Wproj^T + bproj
    {
        GJobs js;
        js.j[0] = mkjob(O2, 784, 0, 0, Wproj, bproj, nullptr, 1, 0, 0, (float*)d_out, 784, 1.f, 0);
        js.j[1] = js.j[2] = js.j[3] = js.j[0];
        gemm_multi<4><<<dim3(16, 25, 1), blk, 0, stream>>>(js);
    }
}